// Round 1
// baseline (179.565 us; speedup 1.0000x reference)
//
#include <hip/hip_runtime.h>
#include <math.h>

#define NTRIP 44
#define NROUNDS 44
#define STREAMN (NROUNDS * 624) /* 27456 u32 */
#define NACC_MAX 512

struct Meta {
  int lam[NTRIP];
  int ell[NTRIP];
  int LL[NTRIP];
  int outbase[NTRIP];
  int cumP[NTRIP];
  int P[NTRIP];
};

// ---------------- MT19937 raw-stream generation ----------------
__device__ __forceinline__ unsigned mt_tw(unsigned hi, unsigned lo) {
  unsigned y = (hi & 0x80000000u) | (lo & 0x7fffffffu);
  return (y >> 1) ^ ((y & 1u) ? 0x9908b0dfu : 0u);
}

__global__ __launch_bounds__(256) void mtgen_kernel(unsigned* __restrict__ rnd) {
  __shared__ unsigned mt[2][624];
  int tid = threadIdx.x;
  if (tid == 0) {
    unsigned s = 0u; // numpy mt19937_seed(0)
    for (int i = 0; i < 624; i++) {
      mt[0][i] = s;
      s = 1812433253u * (s ^ (s >> 30)) + (unsigned)(i + 1);
    }
  }
  __syncthreads();
  int cur = 0;
  for (int r = 0; r < NROUNDS; r++) {
    unsigned* O = mt[cur];
    unsigned* N = mt[cur ^ 1];
    // stage 1: i in [0,227) -> depends only on old state
    for (int i = tid; i < 227; i += 256)
      N[i] = O[i + 397] ^ mt_tw(O[i], O[i + 1]);
    __syncthreads();
    // stage 2: i in [227,454) -> needs N[0..226]
    for (int i = 227 + tid; i < 454; i += 256)
      N[i] = N[i - 227] ^ mt_tw(O[i], O[i + 1]);
    __syncthreads();
    // stage 3: i in [454,624) -> needs N[227..396]; i==623 uses N[0] low bits
    for (int i = 454 + tid; i < 624; i += 256) {
      unsigned lo = (i == 623) ? N[0] : O[i + 1];
      N[i] = N[i - 227] ^ mt_tw(O[i], lo);
    }
    __syncthreads();
    // temper + store
    for (int i = tid; i < 624; i += 256) {
      unsigned y = N[i];
      y ^= y >> 11;
      y ^= (y << 7) & 0x9d2c5680u;
      y ^= (y << 15) & 0xefc60000u;
      y ^= y >> 18;
      rnd[r * 624 + i] = y;
    }
    cur ^= 1;
    __syncthreads();
  }
}

// ---------------- Decode: randint blocks + polar gaussians ----------------
__global__ __launch_bounds__(256) void gen_decode_kernel(
    const unsigned* __restrict__ rnd,
    int* __restrict__ idxnu, int* __restrict__ idx1v, float* __restrict__ cg,
    Meta meta) {
  __shared__ unsigned char acc_ok[STREAMN / 4];
  __shared__ int pos[NACC_MAX];
  __shared__ int idxoff[NTRIP];
  __shared__ int naccs;
  const int tid = threadIdx.x;
  const double inv253 = 1.0 / 9007199254740992.0;

  // phase A0: acceptance bit for every 4-aligned candidate iteration
  for (int q = tid; q < STREAMN / 4; q += 256) {
    unsigned a0 = rnd[4 * q + 0], a1 = rnd[4 * q + 1];
    unsigned a2 = rnd[4 * q + 2], a3 = rnd[4 * q + 3];
    double d1 = ((double)(a0 >> 5) * 67108864.0 + (double)(a1 >> 6)) * inv253;
    double d2 = ((double)(a2 >> 5) * 67108864.0 + (double)(a3 >> 6)) * inv253;
    double x1 = 2.0 * d1 - 1.0, x2 = 2.0 * d2 - 1.0;
    double r2 = x1 * x1 + x2 * x2;
    acc_ok[q] = (r2 < 1.0 && r2 != 0.0) ? 1 : 0;
  }
  __syncthreads();

  // phase A1: single-thread walk (integer logic + LDS bit lookups only)
  if (tid == 0) {
    int cur = 0, g = 0, c = 0;
    for (int t = 0; t < NTRIP; t++) {
      idxoff[t] = cur;
      cur += 512; // 256 randint(0,256) + 256 randint(0,128), one u32 each
      int target = c + meta.P[t];
      while (2 * g < target) {
        if (acc_ok[cur >> 2]) {
          pos[(g < NACC_MAX) ? g : 0] = cur;
          g++;
        }
        cur += 4;
      }
      c = target;
    }
    naccs = (g < NACC_MAX) ? g : NACC_MAX;
  }
  __syncthreads();

  // phase B: finalize gaussians in parallel (order: f*x2 first, cache f*x1)
  int na = naccs;
  for (int gi = tid; gi < na; gi += 256) {
    int q = pos[gi];
    unsigned a0 = rnd[q + 0], a1 = rnd[q + 1], a2 = rnd[q + 2], a3 = rnd[q + 3];
    double d1 = ((double)(a0 >> 5) * 67108864.0 + (double)(a1 >> 6)) * inv253;
    double d2 = ((double)(a2 >> 5) * 67108864.0 + (double)(a3 >> 6)) * inv253;
    double x1 = 2.0 * d1 - 1.0, x2 = 2.0 * d2 - 1.0;
    double r2 = x1 * x1 + x2 * x2;
    double f = sqrt(-2.0 * log(r2) / r2);
    cg[2 * gi + 0] = (float)(f * x2);
    cg[2 * gi + 1] = (float)(f * x1);
  }

  // phase C: extract gather indices
  for (int j = tid; j < NTRIP * 256; j += 256) {
    int t = j >> 8, k = j & 255;
    int off = idxoff[t];
    idxnu[j] = (int)(rnd[off + k] & 255u);
    idx1v[j] = (int)(rnd[off + 256 + k] & 127u);
  }
}

// ---------------- Main compute ----------------
template <int LAM, int EL, int LLV>
__device__ __forceinline__ void le_body(
    const float* __restrict__ Arow, const float* __restrict__ Brow,
    int inu, int i1, const float* __restrict__ cgp, float* __restrict__ orow) {
  constexpr int NLt[7] = {4, 9, 11, 10, 6, 3, 1};
  constexpr int SM = NLt[LLV] * 256;
  float a[2 * LAM + 1];
  float b[2 * EL + 1];
#pragma unroll
  for (int mu = 0; mu <= 2 * LAM; mu++) a[mu] = Arow[mu * 256 + inu];
#pragma unroll
  for (int m = 0; m <= 2 * EL; m++) b[m] = Brow[m * 128 + i1];
  float acc[2 * LLV + 1];
#pragma unroll
  for (int M = 0; M <= 2 * LLV; M++) acc[M] = 0.0f;
  int p = 0;
#pragma unroll
  for (int mu = 0; mu <= 2 * LAM; mu++) {
#pragma unroll
    for (int m = 0; m <= 2 * EL; m++) {
      const int Mv = (mu - LAM) + (m - EL);
      if (Mv >= -LLV && Mv <= LLV) {
        acc[Mv + LLV] += cgp[p] * a[mu] * b[m];
        p++;
      }
    }
  }
#pragma unroll
  for (int M = 0; M <= 2 * LLV; M++) orow[(size_t)M * SM] = acc[M];
}

__global__ __launch_bounds__(256) void le_compute_kernel(
    const float* __restrict__ A0, const float* __restrict__ A1,
    const float* __restrict__ A2, const float* __restrict__ A3,
    const float* __restrict__ B0, const float* __restrict__ B1,
    const float* __restrict__ B2, const float* __restrict__ B3,
    const int* __restrict__ idxnu, const int* __restrict__ idx1v,
    const float* __restrict__ cg, Meta meta, float* __restrict__ out) {
  int bid = blockIdx.x;
  int t = bid >> 10;
  int s = bid & 1023;
  int k = threadIdx.x;
  int lam = meta.lam[t], el = meta.ell[t];
  const float* Ab = (lam == 0) ? A0 : (lam == 1) ? A1 : (lam == 2) ? A2 : A3;
  const float* Bb = (el == 0) ? B0 : (el == 1) ? B1 : (el == 2) ? B2 : B3;
  const float* Arow = Ab + (size_t)s * (size_t)((2 * lam + 1) * 256);
  const float* Brow = Bb + (size_t)s * (size_t)((2 * el + 1) * 128);
  int inu = idxnu[(t << 8) + k];
  int i1 = idx1v[(t << 8) + k];
  const float* cgp = cg + meta.cumP[t];
  float* orow = out + (size_t)s * 65536 + meta.outbase[t] + k;
  switch (t) {
#define CASE_T(i, LM, ELV, LV) \
  case i: le_body<LM, ELV, LV>(Arow, Brow, inu, i1, cgp, orow); break;
    CASE_T(0, 0, 0, 0) CASE_T(1, 0, 1, 1) CASE_T(2, 0, 2, 2) CASE_T(3, 0, 3, 3)
    CASE_T(4, 1, 0, 1) CASE_T(5, 1, 1, 0) CASE_T(6, 1, 1, 1) CASE_T(7, 1, 1, 2)
    CASE_T(8, 1, 2, 1) CASE_T(9, 1, 2, 2) CASE_T(10, 1, 2, 3) CASE_T(11, 1, 3, 2)
    CASE_T(12, 1, 3, 3) CASE_T(13, 1, 3, 4)
    CASE_T(14, 2, 0, 2) CASE_T(15, 2, 1, 1) CASE_T(16, 2, 1, 2) CASE_T(17, 2, 1, 3)
    CASE_T(18, 2, 2, 0) CASE_T(19, 2, 2, 1) CASE_T(20, 2, 2, 2) CASE_T(21, 2, 2, 3)
    CASE_T(22, 2, 2, 4) CASE_T(23, 2, 3, 1) CASE_T(24, 2, 3, 2) CASE_T(25, 2, 3, 3)
    CASE_T(26, 2, 3, 4) CASE_T(27, 2, 3, 5)
    CASE_T(28, 3, 0, 3) CASE_T(29, 3, 1, 2) CASE_T(30, 3, 1, 3) CASE_T(31, 3, 1, 4)
    CASE_T(32, 3, 2, 1) CASE_T(33, 3, 2, 2) CASE_T(34, 3, 2, 3) CASE_T(35, 3, 2, 4)
    CASE_T(36, 3, 2, 5)
    CASE_T(37, 3, 3, 0) CASE_T(38, 3, 3, 1) CASE_T(39, 3, 3, 2) CASE_T(40, 3, 3, 3)
    CASE_T(41, 3, 3, 4) CASE_T(42, 3, 3, 5) CASE_T(43, 3, 3, 6)
#undef CASE_T
  }
}

extern "C" void kernel_launch(void* const* d_in, const int* in_sizes, int n_in,
                              void* d_out, int out_size, void* d_ws, size_t ws_size,
                              hipStream_t stream) {
  const float* A0 = (const float*)d_in[0];
  const float* A1 = (const float*)d_in[1];
  const float* A2 = (const float*)d_in[2];
  const float* A3 = (const float*)d_in[3];
  const float* B0 = (const float*)d_in[4];
  const float* B1 = (const float*)d_in[5];
  const float* B2 = (const float*)d_in[6];
  const float* B3 = (const float*)d_in[7];
  float* out = (float*)d_out;

  // workspace carve (all 4-byte units)
  unsigned* rnd = (unsigned*)d_ws;               // STREAMN u32
  int* idxnu = (int*)d_ws + STREAMN;             // 44*256
  int* idx1v = idxnu + NTRIP * 256;              // 44*256
  float* cg = (float*)(idx1v + NTRIP * 256);     // 810 (+pad)

  // deterministic static metadata (mirrors reference build_structure loops)
  Meta meta;
  int nL[7] = {0, 0, 0, 0, 0, 0, 0};
  for (int lam = 0; lam <= 3; lam++)
    for (int l = 0; l <= 3; l++)
      for (int L = (lam > l ? lam - l : l - lam); L <= lam + l; L++) nL[L]++;
  int Lbase[8];
  Lbase[0] = 0;
  for (int L = 0; L < 7; L++) Lbase[L + 1] = Lbase[L] + (2 * L + 1) * nL[L] * 256;
  int bcnt[7] = {0, 0, 0, 0, 0, 0, 0};
  int t = 0, cum = 0;
  for (int lam = 0; lam <= 3; lam++)
    for (int l = 0; l <= 3; l++)
      for (int L = (lam > l ? lam - l : l - lam); L <= lam + l; L++) {
        meta.lam[t] = lam;
        meta.ell[t] = l;
        meta.LL[t] = L;
        meta.outbase[t] = Lbase[L] + bcnt[L] * 256;
        bcnt[L]++;
        int P = 0;
        for (int mu = 0; mu <= 2 * lam; mu++)
          for (int m = 0; m <= 2 * l; m++) {
            int Mv = (mu - lam) + (m - l);
            if (Mv >= -L && Mv <= L) P++;
          }
        meta.P[t] = P;
        meta.cumP[t] = cum;
        cum += P;
        t++;
      }

  mtgen_kernel<<<1, 256, 0, stream>>>(rnd);
  gen_decode_kernel<<<1, 256, 0, stream>>>(rnd, idxnu, idx1v, cg, meta);
  le_compute_kernel<<<NTRIP * 1024, 256, 0, stream>>>(
      A0, A1, A2, A3, B0, B1, B2, B3, idxnu, idx1v, cg, meta, out);
}

// Round 2
// 160.461 us; speedup vs baseline: 1.1191x; 1.1191x over previous
//
#include <hip/hip_runtime.h>
#include <math.h>

#define NTRIP 44
#define NROUNDS 48
#define STREAMN (NROUNDS * 624) /* 29952 u32 */
#define NCAND (STREAMN / 4)     /* 7488 candidate slots */
#define NWORDS ((NCAND + 63) / 64)
#define NACC_MAX 512

struct Meta {
  int lam[NTRIP];
  int ell[NTRIP];
  int LL[NTRIP];
  int outbase[NTRIP];
  int cumP[NTRIP];
  int P[NTRIP];
};

__device__ __forceinline__ unsigned mt_tw(unsigned hi, unsigned lo) {
  unsigned y = (hi & 0x80000000u) | (lo & 0x7fffffffu);
  return (y >> 1) ^ ((y & 1u) ? 0x9908b0dfu : 0u);
}

// ---------------- Merged generator: MT19937 + decode ----------------
__global__ __launch_bounds__(256) void gen_kernel(
    unsigned* __restrict__ rnd, int* __restrict__ pairs, float* __restrict__ cg,
    Meta meta) {
  __shared__ unsigned mt[2][624];
  __shared__ unsigned long long bits[NWORDS + 1];
  __shared__ int pos[NACC_MAX];
  __shared__ int idxoff[NTRIP];
  __shared__ int naccs;
  const int tid = threadIdx.x;
  const double inv253 = 1.0 / 9007199254740992.0;

  // --- MT19937: numpy seed(0), parallel twist, temper to global ws ---
  if (tid == 0) {
    unsigned s = 0u;
    for (int i = 0; i < 624; i++) {
      mt[0][i] = s;
      s = 1812433253u * (s ^ (s >> 30)) + (unsigned)(i + 1);
    }
  }
  __syncthreads();
  int cur = 0;
  for (int r = 0; r < NROUNDS; r++) {
    unsigned* O = mt[cur];
    unsigned* N = mt[cur ^ 1];
    if (tid < 227) N[tid] = O[tid + 397] ^ mt_tw(O[tid], O[tid + 1]);
    __syncthreads();
    if (tid < 227) N[227 + tid] = N[tid] ^ mt_tw(O[227 + tid], O[228 + tid]);
    __syncthreads();
    for (int i = 454 + tid; i < 624; i += 256) {
      unsigned lo = (i == 623) ? N[0] : O[i + 1];
      N[i] = N[i - 227] ^ mt_tw(O[i], lo);
    }
    __syncthreads();
    for (int i = tid; i < 624; i += 256) {
      unsigned y = N[i];
      y ^= y >> 11;
      y ^= (y << 7) & 0x9d2c5680u;
      y ^= (y << 15) & 0xefc60000u;
      y ^= y >> 18;
      rnd[r * 624 + i] = y;
    }
    cur ^= 1;
    __syncthreads();
  }

  // --- acceptance bits via wave ballot (1 bit per 4-u32 candidate) ---
  const uint4* rnd4 = (const uint4*)rnd;
  for (int base = 0; base < NCAND; base += 256) {
    int q = base + tid;
    bool ok = false;
    if (q < NCAND) {
      uint4 a = rnd4[q];
      double d1 = ((double)(a.x >> 5) * 67108864.0 + (double)(a.y >> 6)) * inv253;
      double d2 = ((double)(a.z >> 5) * 67108864.0 + (double)(a.w >> 6)) * inv253;
      double x1 = 2.0 * d1 - 1.0, x2 = 2.0 * d2 - 1.0;
      double r2 = x1 * x1 + x2 * x2;
      ok = (r2 < 1.0 && r2 != 0.0);
    }
    unsigned long long m = __ballot(ok);
    if ((tid & 63) == 0) bits[q >> 6] = m;
  }
  __syncthreads();

  // --- word-walk: locate randint blocks + accepted polar iterations ---
  if (tid == 0) {
    int g = 0, c = 0;
    cur = 0;
    for (int t = 0; t < NTRIP; t++) {
      idxoff[t] = cur;
      cur += 512; // 256 randint(0,256) + 256 randint(0,128)
      int target = c + meta.P[t];
      while (2 * g < target) {
        int ci = cur >> 2;
        int wi = ci >> 6, sh = ci & 63;
        unsigned long long w = bits[wi] >> sh;
        int avail = 64 - sh;
        bool advanced = false;
        while (w) {
          int b = __builtin_ctzll(w);
          w &= w - 1;
          pos[(g < NACC_MAX) ? g : 0] = 4 * (ci + b);
          g++;
          if (2 * g >= target) {
            cur = 4 * (ci + b + 1);
            advanced = true;
            break;
          }
        }
        if (!advanced) cur += 4 * avail;
      }
      c = target;
    }
    naccs = (g < NACC_MAX) ? g : NACC_MAX;
  }
  __syncthreads();

  // --- finalize gaussians in parallel (order: f*x2 first, cached f*x1) ---
  int na = naccs;
  for (int gi = tid; gi < na; gi += 256) {
    int q = pos[gi];
    unsigned a0 = rnd[q + 0], a1 = rnd[q + 1], a2 = rnd[q + 2], a3 = rnd[q + 3];
    double d1 = ((double)(a0 >> 5) * 67108864.0 + (double)(a1 >> 6)) * inv253;
    double d2 = ((double)(a2 >> 5) * 67108864.0 + (double)(a3 >> 6)) * inv253;
    double x1 = 2.0 * d1 - 1.0, x2 = 2.0 * d2 - 1.0;
    double r2 = x1 * x1 + x2 * x2;
    double f = sqrt(-2.0 * log(r2) / r2);
    cg[2 * gi + 0] = (float)(f * x2);
    cg[2 * gi + 1] = (float)(f * x1);
  }

  // --- packed gather indices: idx_nu | idx_1<<16 ---
  for (int j = tid; j < NTRIP * 256; j += 256) {
    int t = j >> 8, k = j & 255;
    int off = idxoff[t];
    pairs[j] = (int)(rnd[off + k] & 255u) | ((int)(rnd[off + 256 + k] & 127u) << 16);
  }
}

// ---------------- Main compute: one block = (sample, lam-group) ----------------
template <int LAM, int EL, int LV>
__device__ __forceinline__ void le_body2(
    const float* __restrict__ ldsA, const float* __restrict__ ldsB,
    int pr, const float* __restrict__ cgp, float* __restrict__ orow) {
  constexpr int NLt[7] = {4, 9, 11, 10, 6, 3, 1};
  constexpr int SM = NLt[LV] * 256;
  constexpr int BOFF[4] = {0, 128, 512, 1152};
  int inu = pr & 0xffff;
  int i1 = pr >> 16;
  float a[2 * LAM + 1];
  float b[2 * EL + 1];
#pragma unroll
  for (int mu = 0; mu <= 2 * LAM; mu++) a[mu] = ldsA[mu * 256 + inu];
#pragma unroll
  for (int m = 0; m <= 2 * EL; m++) b[m] = ldsB[BOFF[EL] + m * 128 + i1];
  float acc[2 * LV + 1];
#pragma unroll
  for (int M = 0; M <= 2 * LV; M++) acc[M] = 0.0f;
  int p = 0;
#pragma unroll
  for (int mu = 0; mu <= 2 * LAM; mu++) {
#pragma unroll
    for (int m = 0; m <= 2 * EL; m++) {
      const int Mv = (mu - LAM) + (m - EL);
      if (Mv >= -LV && Mv <= LV) {
        acc[Mv + LV] += cgp[p] * a[mu] * b[m];
        p++;
      }
    }
  }
#pragma unroll
  for (int M = 0; M <= 2 * LV; M++) orow[(size_t)M * SM] = acc[M];
}

__global__ __launch_bounds__(256) void le_compute_kernel(
    const float* __restrict__ A0, const float* __restrict__ A1,
    const float* __restrict__ A2, const float* __restrict__ A3,
    const float* __restrict__ B0, const float* __restrict__ B1,
    const float* __restrict__ B2, const float* __restrict__ B3,
    const int* __restrict__ pairs, const float* __restrict__ cg,
    Meta meta, float* __restrict__ out) {
  __shared__ float ldsA[1792];
  __shared__ float ldsB[2048];
  int bid = blockIdx.x;
  int lam = bid & 3;
  int s = bid >> 2;
  int k = threadIdx.x;

  // stage A[lam][s] rows
  const float* Ab = (lam == 0) ? A0 : (lam == 1) ? A1 : (lam == 2) ? A2 : A3;
  int na = (2 * lam + 1) * 256;
  const float4* As = (const float4*)(Ab + (size_t)s * na);
  for (int i = k; i < (na >> 2); i += 256) ((float4*)ldsA)[i] = As[i];
  // stage all B[l][s] rows
  {
    const float4* Bs0 = (const float4*)(B0 + (size_t)s * 128);
    const float4* Bs1 = (const float4*)(B1 + (size_t)s * 384);
    const float4* Bs2 = (const float4*)(B2 + (size_t)s * 640);
    const float4* Bs3 = (const float4*)(B3 + (size_t)s * 896);
    if (k < 32) ((float4*)(ldsB + 0))[k] = Bs0[k];
    if (k < 96) ((float4*)(ldsB + 128))[k] = Bs1[k];
    if (k < 160) ((float4*)(ldsB + 512))[k] = Bs2[k];
    if (k < 224) ((float4*)(ldsB + 1152))[k] = Bs3[k];
  }
  __syncthreads();

  float* outs = out + (size_t)s * 65536 + k;
#define RUN(TT, ELV, LV)                                             \
  le_body2<LAMC, ELV, LV>(ldsA, ldsB, pairs[(TT << 8) + k],          \
                          cg + meta.cumP[TT], outs + meta.outbase[TT]);
  switch (lam) {
    case 0: {
      constexpr int LAMC = 0;
      RUN(0, 0, 0) RUN(1, 1, 1) RUN(2, 2, 2) RUN(3, 3, 3)
    } break;
    case 1: {
      constexpr int LAMC = 1;
      RUN(4, 0, 1) RUN(5, 1, 0) RUN(6, 1, 1) RUN(7, 1, 2)
      RUN(8, 2, 1) RUN(9, 2, 2) RUN(10, 2, 3)
      RUN(11, 3, 2) RUN(12, 3, 3) RUN(13, 3, 4)
    } break;
    case 2: {
      constexpr int LAMC = 2;
      RUN(14, 0, 2) RUN(15, 1, 1) RUN(16, 1, 2) RUN(17, 1, 3)
      RUN(18, 2, 0) RUN(19, 2, 1) RUN(20, 2, 2) RUN(21, 2, 3) RUN(22, 2, 4)
      RUN(23, 3, 1) RUN(24, 3, 2) RUN(25, 3, 3) RUN(26, 3, 4) RUN(27, 3, 5)
    } break;
    default: {
      constexpr int LAMC = 3;
      RUN(28, 0, 3) RUN(29, 1, 2) RUN(30, 1, 3) RUN(31, 1, 4)
      RUN(32, 2, 1) RUN(33, 2, 2) RUN(34, 2, 3) RUN(35, 2, 4) RUN(36, 2, 5)
      RUN(37, 3, 0) RUN(38, 3, 1) RUN(39, 3, 2) RUN(40, 3, 3)
      RUN(41, 3, 4) RUN(42, 3, 5) RUN(43, 3, 6)
    } break;
  }
#undef RUN
}

extern "C" void kernel_launch(void* const* d_in, const int* in_sizes, int n_in,
                              void* d_out, int out_size, void* d_ws, size_t ws_size,
                              hipStream_t stream) {
  const float* A0 = (const float*)d_in[0];
  const float* A1 = (const float*)d_in[1];
  const float* A2 = (const float*)d_in[2];
  const float* A3 = (const float*)d_in[3];
  const float* B0 = (const float*)d_in[4];
  const float* B1 = (const float*)d_in[5];
  const float* B2 = (const float*)d_in[6];
  const float* B3 = (const float*)d_in[7];
  float* out = (float*)d_out;

  // workspace carve (4-byte units)
  unsigned* rnd = (unsigned*)d_ws;            // STREAMN u32
  int* pairs = (int*)d_ws + STREAMN;          // 44*256 packed (idx_nu | idx_1<<16)
  float* cg = (float*)(pairs + NTRIP * 256);  // 812 floats

  // deterministic static metadata (mirrors reference build_structure loops)
  Meta meta;
  int nL[7] = {0, 0, 0, 0, 0, 0, 0};
  for (int lam = 0; lam <= 3; lam++)
    for (int l = 0; l <= 3; l++)
      for (int L = (lam > l ? lam - l : l - lam); L <= lam + l; L++) nL[L]++;
  int Lbase[8];
  Lbase[0] = 0;
  for (int L = 0; L < 7; L++) Lbase[L + 1] = Lbase[L] + (2 * L + 1) * nL[L] * 256;
  int bcnt[7] = {0, 0, 0, 0, 0, 0, 0};
  int t = 0, cum = 0;
  for (int lam = 0; lam <= 3; lam++)
    for (int l = 0; l <= 3; l++)
      for (int L = (lam > l ? lam - l : l - lam); L <= lam + l; L++) {
        meta.lam[t] = lam;
        meta.ell[t] = l;
        meta.LL[t] = L;
        meta.outbase[t] = Lbase[L] + bcnt[L] * 256;
        bcnt[L]++;
        int P = 0;
        for (int mu = 0; mu <= 2 * lam; mu++)
          for (int m = 0; m <= 2 * l; m++) {
            int Mv = (mu - lam) + (m - l);
            if (Mv >= -L && Mv <= L) P++;
          }
        meta.P[t] = P;
        meta.cumP[t] = cum;
        cum += P;
        t++;
      }

  gen_kernel<<<1, 256, 0, stream>>>(rnd, pairs, cg, meta);
  le_compute_kernel<<<4096, 256, 0, stream>>>(
      A0, A1, A2, A3, B0, B1, B2, B3, pairs, cg, meta, out);
}

// Round 3
// 138.744 us; speedup vs baseline: 1.2942x; 1.1565x over previous
//
#include <hip/hip_runtime.h>
#include <math.h>

#define NTRIP 44
#define NROUNDS 48
#define STREAMN (NROUNDS * 624) /* 29952 u32 */
#define NCAND (STREAMN / 4)     /* 7488 candidate slots */
#define NWORDS ((NCAND + 63) / 64)
#define NACC_MAX 512

struct Meta {
  int lam[NTRIP];
  int ell[NTRIP];
  int LL[NTRIP];
  int outbase[NTRIP];
  int cumP[NTRIP];
  int P[NTRIP];
};

__device__ __forceinline__ unsigned mt_tw(unsigned hi, unsigned lo) {
  unsigned y = (hi & 0x80000000u) | (lo & 0x7fffffffu);
  return (y >> 1) ^ ((y & 1u) ? 0x9908b0dfu : 0u);
}

// ---------------- Merged generator: MT19937 + decode ----------------
__global__ __launch_bounds__(256) void gen_kernel(
    unsigned* __restrict__ rnd, int* __restrict__ pairs, float* __restrict__ cg,
    Meta meta) {
  __shared__ unsigned mt[2][624];
  __shared__ unsigned long long bits[NWORDS + 1];
  __shared__ int pos[NACC_MAX];
  __shared__ int idxoff[NTRIP];
  __shared__ int naccs;
  const int tid = threadIdx.x;
  const double inv253 = 1.0 / 9007199254740992.0;

  // --- MT19937: numpy seed(0), parallel twist, temper to global ws ---
  if (tid == 0) {
    unsigned s = 0u;
    for (int i = 0; i < 624; i++) {
      mt[0][i] = s;
      s = 1812433253u * (s ^ (s >> 30)) + (unsigned)(i + 1);
    }
  }
  __syncthreads();
  int cur = 0;
  for (int r = 0; r < NROUNDS; r++) {
    unsigned* O = mt[cur];
    unsigned* N = mt[cur ^ 1];
    if (tid < 227) N[tid] = O[tid + 397] ^ mt_tw(O[tid], O[tid + 1]);
    __syncthreads();
    if (tid < 227) N[227 + tid] = N[tid] ^ mt_tw(O[227 + tid], O[228 + tid]);
    __syncthreads();
    for (int i = 454 + tid; i < 624; i += 256) {
      unsigned lo = (i == 623) ? N[0] : O[i + 1];
      N[i] = N[i - 227] ^ mt_tw(O[i], lo);
    }
    __syncthreads();
    for (int i = tid; i < 624; i += 256) {
      unsigned y = N[i];
      y ^= y >> 11;
      y ^= (y << 7) & 0x9d2c5680u;
      y ^= (y << 15) & 0xefc60000u;
      y ^= y >> 18;
      rnd[r * 624 + i] = y;
    }
    cur ^= 1;
    __syncthreads();
  }

  // --- acceptance bits via wave ballot (1 bit per 4-u32 candidate) ---
  const uint4* rnd4 = (const uint4*)rnd;
  for (int base = 0; base < NCAND; base += 256) {
    int q = base + tid;
    bool ok = false;
    if (q < NCAND) {
      uint4 a = rnd4[q];
      double d1 = ((double)(a.x >> 5) * 67108864.0 + (double)(a.y >> 6)) * inv253;
      double d2 = ((double)(a.z >> 5) * 67108864.0 + (double)(a.w >> 6)) * inv253;
      double x1 = 2.0 * d1 - 1.0, x2 = 2.0 * d2 - 1.0;
      double r2 = x1 * x1 + x2 * x2;
      ok = (r2 < 1.0 && r2 != 0.0);
    }
    unsigned long long m = __ballot(ok);
    if ((tid & 63) == 0) bits[q >> 6] = m;
  }
  __syncthreads();

  // --- word-walk: locate randint blocks + accepted polar iterations ---
  if (tid == 0) {
    int g = 0, c = 0;
    cur = 0;
    for (int t = 0; t < NTRIP; t++) {
      idxoff[t] = cur;
      cur += 512; // 256 randint(0,256) + 256 randint(0,128)
      int target = c + meta.P[t];
      while (2 * g < target) {
        int ci = cur >> 2;
        int wi = ci >> 6, sh = ci & 63;
        unsigned long long w = bits[wi] >> sh;
        int avail = 64 - sh;
        bool advanced = false;
        while (w) {
          int b = __builtin_ctzll(w);
          w &= w - 1;
          pos[(g < NACC_MAX) ? g : 0] = 4 * (ci + b);
          g++;
          if (2 * g >= target) {
            cur = 4 * (ci + b + 1);
            advanced = true;
            break;
          }
        }
        if (!advanced) cur += 4 * avail;
      }
      c = target;
    }
    naccs = (g < NACC_MAX) ? g : NACC_MAX;
  }
  __syncthreads();

  // --- finalize gaussians in parallel (order: f*x2 first, cached f*x1) ---
  int na = naccs;
  for (int gi = tid; gi < na; gi += 256) {
    int q = pos[gi];
    unsigned a0 = rnd[q + 0], a1 = rnd[q + 1], a2 = rnd[q + 2], a3 = rnd[q + 3];
    double d1 = ((double)(a0 >> 5) * 67108864.0 + (double)(a1 >> 6)) * inv253;
    double d2 = ((double)(a2 >> 5) * 67108864.0 + (double)(a3 >> 6)) * inv253;
    double x1 = 2.0 * d1 - 1.0, x2 = 2.0 * d2 - 1.0;
    double r2 = x1 * x1 + x2 * x2;
    double f = sqrt(-2.0 * log(r2) / r2);
    cg[2 * gi + 0] = (float)(f * x2);
    cg[2 * gi + 1] = (float)(f * x1);
  }

  // --- packed gather indices: idx_nu | idx_1<<16 ---
  for (int j = tid; j < NTRIP * 256; j += 256) {
    int t = j >> 8, k = j & 255;
    int off = idxoff[t];
    pairs[j] = (int)(rnd[off + k] & 255u) | ((int)(rnd[off + 256 + k] & 127u) << 16);
  }
}

// ---------------- Main compute: one block = (sample, half) ----------------
template <int LAM, int EL, int LV>
__device__ __forceinline__ void le_body2(
    const float* __restrict__ ldsA, const float* __restrict__ ldsB,
    int pr, const float* __restrict__ cgp, float* __restrict__ orow) {
  constexpr int NLt[7] = {4, 9, 11, 10, 6, 3, 1};
  constexpr int SM = NLt[LV] * 256;
  constexpr int AOFF[4] = {0, 256, 1024, 2304};
  constexpr int BOFF[4] = {0, 128, 512, 1152};
  int inu = pr & 0xffff;
  int i1 = pr >> 16;
  float a[2 * LAM + 1];
  float b[2 * EL + 1];
#pragma unroll
  for (int mu = 0; mu <= 2 * LAM; mu++) a[mu] = ldsA[AOFF[LAM] + mu * 256 + inu];
#pragma unroll
  for (int m = 0; m <= 2 * EL; m++) b[m] = ldsB[BOFF[EL] + m * 128 + i1];
  float acc[2 * LV + 1];
#pragma unroll
  for (int M = 0; M <= 2 * LV; M++) acc[M] = 0.0f;
  int p = 0;
#pragma unroll
  for (int mu = 0; mu <= 2 * LAM; mu++) {
#pragma unroll
    for (int m = 0; m <= 2 * EL; m++) {
      const int Mv = (mu - LAM) + (m - EL);
      if (Mv >= -LV && Mv <= LV) {
        acc[Mv + LV] += cgp[p] * a[mu] * b[m];
        p++;
      }
    }
  }
#pragma unroll
  for (int M = 0; M <= 2 * LV; M++) orow[(size_t)M * SM] = acc[M];
}

__global__ __launch_bounds__(256) void le_compute_kernel(
    const float* __restrict__ A0, const float* __restrict__ A1,
    const float* __restrict__ A2, const float* __restrict__ A3,
    const float* __restrict__ B0, const float* __restrict__ B1,
    const float* __restrict__ B2, const float* __restrict__ B3,
    const int* __restrict__ pairs, const float* __restrict__ cg,
    Meta meta, float* __restrict__ out) {
  __shared__ float ldsA[4096];
  __shared__ float ldsB[2048];
  int bid = blockIdx.x;
  int s = bid >> 1;
  int half = bid & 1;
  int k = threadIdx.x;

  // stage ALL A rows (16KB) + ALL B rows (8KB) for sample s
  {
    const float4* p0 = (const float4*)(A0 + (size_t)s * 256);
    if (k < 64) ((float4*)(ldsA + 0))[k] = p0[k];
    const float4* p1 = (const float4*)(A1 + (size_t)s * 768);
    if (k < 192) ((float4*)(ldsA + 256))[k] = p1[k];
    const float4* p2 = (const float4*)(A2 + (size_t)s * 1280);
    for (int i = k; i < 320; i += 256) ((float4*)(ldsA + 1024))[i] = p2[i];
    const float4* p3 = (const float4*)(A3 + (size_t)s * 1792);
    for (int i = k; i < 448; i += 256) ((float4*)(ldsA + 2304))[i] = p3[i];
    const float4* q0 = (const float4*)(B0 + (size_t)s * 128);
    if (k < 32) ((float4*)(ldsB + 0))[k] = q0[k];
    const float4* q1 = (const float4*)(B1 + (size_t)s * 384);
    if (k < 96) ((float4*)(ldsB + 128))[k] = q1[k];
    const float4* q2 = (const float4*)(B2 + (size_t)s * 640);
    if (k < 160) ((float4*)(ldsB + 512))[k] = q2[k];
    const float4* q3 = (const float4*)(B3 + (size_t)s * 896);
    if (k < 224) ((float4*)(ldsB + 1152))[k] = q3[k];
  }
  __syncthreads();

  float* outs = out + (size_t)s * 65536 + k;
#define RUN(TT, LM, ELV, LV)                                      \
  le_body2<LM, ELV, LV>(ldsA, ldsB, pairs[(TT << 8) + k],         \
                        cg + meta.cumP[TT], outs + meta.outbase[TT]);
  // bodies in outbase-sorted order, interleaved into two balanced halves;
  // each block's stores sweep its 256KB output row near-sequentially.
  if (half == 0) {
    RUN(0, 0, 0, 0)   RUN(18, 2, 2, 0)  RUN(1, 0, 1, 1)   RUN(6, 1, 1, 1)
    RUN(15, 2, 1, 1)  RUN(23, 2, 3, 1)  RUN(38, 3, 3, 1)  RUN(7, 1, 1, 2)
    RUN(11, 1, 3, 2)  RUN(16, 2, 1, 2)  RUN(24, 2, 3, 2)  RUN(33, 3, 2, 2)
    RUN(3, 0, 3, 3)   RUN(12, 1, 3, 3)  RUN(21, 2, 2, 3)  RUN(28, 3, 0, 3)
    RUN(34, 3, 2, 3)  RUN(13, 1, 3, 4)  RUN(26, 2, 3, 4)  RUN(35, 3, 2, 4)
    RUN(27, 2, 3, 5)  RUN(42, 3, 3, 5)
  } else {
    RUN(5, 1, 1, 0)   RUN(37, 3, 3, 0)  RUN(4, 1, 0, 1)   RUN(8, 1, 2, 1)
    RUN(19, 2, 2, 1)  RUN(32, 3, 2, 1)  RUN(2, 0, 2, 2)   RUN(9, 1, 2, 2)
    RUN(14, 2, 0, 2)  RUN(20, 2, 2, 2)  RUN(29, 3, 1, 2)  RUN(39, 3, 3, 2)
    RUN(10, 1, 2, 3)  RUN(17, 2, 1, 3)  RUN(25, 2, 3, 3)  RUN(30, 3, 1, 3)
    RUN(40, 3, 3, 3)  RUN(22, 2, 2, 4)  RUN(31, 3, 1, 4)  RUN(41, 3, 3, 4)
    RUN(36, 3, 2, 5)  RUN(43, 3, 3, 6)
  }
#undef RUN
}

extern "C" void kernel_launch(void* const* d_in, const int* in_sizes, int n_in,
                              void* d_out, int out_size, void* d_ws, size_t ws_size,
                              hipStream_t stream) {
  const float* A0 = (const float*)d_in[0];
  const float* A1 = (const float*)d_in[1];
  const float* A2 = (const float*)d_in[2];
  const float* A3 = (const float*)d_in[3];
  const float* B0 = (const float*)d_in[4];
  const float* B1 = (const float*)d_in[5];
  const float* B2 = (const float*)d_in[6];
  const float* B3 = (const float*)d_in[7];
  float* out = (float*)d_out;

  // workspace carve (4-byte units)
  unsigned* rnd = (unsigned*)d_ws;            // STREAMN u32
  int* pairs = (int*)d_ws + STREAMN;          // 44*256 packed (idx_nu | idx_1<<16)
  float* cg = (float*)(pairs + NTRIP * 256);  // ~820 floats

  // deterministic static metadata (mirrors reference build_structure loops)
  Meta meta;
  int nL[7] = {0, 0, 0, 0, 0, 0, 0};
  for (int lam = 0; lam <= 3; lam++)
    for (int l = 0; l <= 3; l++)
      for (int L = (lam > l ? lam - l : l - lam); L <= lam + l; L++) nL[L]++;
  int Lbase[8];
  Lbase[0] = 0;
  for (int L = 0; L < 7; L++) Lbase[L + 1] = Lbase[L] + (2 * L + 1) * nL[L] * 256;
  int bcnt[7] = {0, 0, 0, 0, 0, 0, 0};
  int t = 0, cum = 0;
  for (int lam = 0; lam <= 3; lam++)
    for (int l = 0; l <= 3; l++)
      for (int L = (lam > l ? lam - l : l - lam); L <= lam + l; L++) {
        meta.lam[t] = lam;
        meta.ell[t] = l;
        meta.LL[t] = L;
        meta.outbase[t] = Lbase[L] + bcnt[L] * 256;
        bcnt[L]++;
        int P = 0;
        for (int mu = 0; mu <= 2 * lam; mu++)
          for (int m = 0; m <= 2 * l; m++) {
            int Mv = (mu - lam) + (m - l);
            if (Mv >= -L && Mv <= L) P++;
          }
        meta.P[t] = P;
        meta.cumP[t] = cum;
        cum += P;
        t++;
      }

  gen_kernel<<<1, 256, 0, stream>>>(rnd, pairs, cg, meta);
  le_compute_kernel<<<2048, 256, 0, stream>>>(
      A0, A1, A2, A3, B0, B1, B2, B3, pairs, cg, meta, out);
}

// Round 4
// 138.575 us; speedup vs baseline: 1.2958x; 1.0012x over previous
//
#include <hip/hip_runtime.h>
#include <math.h>

#define NTRIP 44
#define NROUNDS 48
#define STREAMN (NROUNDS * 624) /* 29952 u32 */
#define NCAND (STREAMN / 4)     /* 7488 candidate slots */
#define NWORDS ((NCAND + 63) / 64)
#define NACC_MAX 512

struct Meta {
  int lam[NTRIP];
  int ell[NTRIP];
  int LL[NTRIP];
  int outbase[NTRIP];
  int cumP[NTRIP];
  int P[NTRIP];
};

__device__ __forceinline__ unsigned mt_tw(unsigned hi, unsigned lo) {
  unsigned y = (hi & 0x80000000u) | (lo & 0x7fffffffu);
  return (y >> 1) ^ ((y & 1u) ? 0x9908b0dfu : 0u);
}

// ---------------- Merged generator: MT19937 + decode ----------------
__global__ __launch_bounds__(256) void gen_kernel(
    unsigned* __restrict__ rnd, int* __restrict__ pairs, float* __restrict__ cg,
    Meta meta) {
  __shared__ unsigned mt[2][624];
  __shared__ unsigned long long bits[NWORDS + 1];
  __shared__ int pos[NACC_MAX];
  __shared__ int idxoff[NTRIP];
  __shared__ int naccs;
  const int tid = threadIdx.x;
  const double inv253 = 1.0 / 9007199254740992.0;

  // --- MT19937: numpy seed(0), parallel twist, temper to global ws ---
  if (tid == 0) {
    unsigned s = 0u;
    for (int i = 0; i < 624; i++) {
      mt[0][i] = s;
      s = 1812433253u * (s ^ (s >> 30)) + (unsigned)(i + 1);
    }
  }
  __syncthreads();
  int cur = 0;
  for (int r = 0; r < NROUNDS; r++) {
    unsigned* O = mt[cur];
    unsigned* N = mt[cur ^ 1];
    if (tid < 227) N[tid] = O[tid + 397] ^ mt_tw(O[tid], O[tid + 1]);
    __syncthreads();
    if (tid < 227) N[227 + tid] = N[tid] ^ mt_tw(O[227 + tid], O[228 + tid]);
    __syncthreads();
    for (int i = 454 + tid; i < 624; i += 256) {
      unsigned lo = (i == 623) ? N[0] : O[i + 1];
      N[i] = N[i - 227] ^ mt_tw(O[i], lo);
    }
    __syncthreads();
    for (int i = tid; i < 624; i += 256) {
      unsigned y = N[i];
      y ^= y >> 11;
      y ^= (y << 7) & 0x9d2c5680u;
      y ^= (y << 15) & 0xefc60000u;
      y ^= y >> 18;
      rnd[r * 624 + i] = y;
    }
    cur ^= 1;
    __syncthreads();
  }

  // --- acceptance bits via wave ballot (1 bit per 4-u32 candidate) ---
  const uint4* rnd4 = (const uint4*)rnd;
  for (int base = 0; base < NCAND; base += 256) {
    int q = base + tid;
    bool ok = false;
    if (q < NCAND) {
      uint4 a = rnd4[q];
      double d1 = ((double)(a.x >> 5) * 67108864.0 + (double)(a.y >> 6)) * inv253;
      double d2 = ((double)(a.z >> 5) * 67108864.0 + (double)(a.w >> 6)) * inv253;
      double x1 = 2.0 * d1 - 1.0, x2 = 2.0 * d2 - 1.0;
      double r2 = x1 * x1 + x2 * x2;
      ok = (r2 < 1.0 && r2 != 0.0);
    }
    unsigned long long m = __ballot(ok);
    if ((tid & 63) == 0) bits[q >> 6] = m;
  }
  __syncthreads();

  // --- word-walk: locate randint blocks + accepted polar iterations ---
  if (tid == 0) {
    int g = 0, c = 0;
    cur = 0;
    for (int t = 0; t < NTRIP; t++) {
      idxoff[t] = cur;
      cur += 512; // 256 randint(0,256) + 256 randint(0,128)
      int target = c + meta.P[t];
      while (2 * g < target) {
        int ci = cur >> 2;
        int wi = ci >> 6, sh = ci & 63;
        unsigned long long w = bits[wi] >> sh;
        int avail = 64 - sh;
        bool advanced = false;
        while (w) {
          int b = __builtin_ctzll(w);
          w &= w - 1;
          pos[(g < NACC_MAX) ? g : 0] = 4 * (ci + b);
          g++;
          if (2 * g >= target) {
            cur = 4 * (ci + b + 1);
            advanced = true;
            break;
          }
        }
        if (!advanced) cur += 4 * avail;
      }
      c = target;
    }
    naccs = (g < NACC_MAX) ? g : NACC_MAX;
  }
  __syncthreads();

  // --- finalize gaussians in parallel (order: f*x2 first, cached f*x1) ---
  int na = naccs;
  for (int gi = tid; gi < na; gi += 256) {
    int q = pos[gi];
    unsigned a0 = rnd[q + 0], a1 = rnd[q + 1], a2 = rnd[q + 2], a3 = rnd[q + 3];
    double d1 = ((double)(a0 >> 5) * 67108864.0 + (double)(a1 >> 6)) * inv253;
    double d2 = ((double)(a2 >> 5) * 67108864.0 + (double)(a3 >> 6)) * inv253;
    double x1 = 2.0 * d1 - 1.0, x2 = 2.0 * d2 - 1.0;
    double r2 = x1 * x1 + x2 * x2;
    double f = sqrt(-2.0 * log(r2) / r2);
    cg[2 * gi + 0] = (float)(f * x2);
    cg[2 * gi + 1] = (float)(f * x1);
  }

  // --- packed gather indices: idx_nu | idx_1<<16 ---
  for (int j = tid; j < NTRIP * 256; j += 256) {
    int t = j >> 8, k = j & 255;
    int off = idxoff[t];
    pairs[j] = (int)(rnd[off + k] & 255u) | ((int)(rnd[off + 256 + k] & 127u) << 16);
  }
}

// ---------------- Main compute: one block = (sample, half) ----------------
// LDS holds TRANSPOSED A/B: ldsA[AOFF(lam) + j*(2lam+1) + mu], odd stride ->
// adjacent mu reads merge into ds_read2_b32 and banks spread bijectively.
template <int LAM, int EL, int LV>
__device__ __forceinline__ void le_body3(
    const float* __restrict__ ldsA, const float* __restrict__ ldsB,
    int pr, const float* __restrict__ cgp, float* __restrict__ orow) {
  constexpr int NLt[7] = {4, 9, 11, 10, 6, 3, 1};
  constexpr int SM = NLt[LV] * 256;
  constexpr int AOFF[4] = {0, 256, 1024, 2304};
  constexpr int BOFF[4] = {0, 128, 512, 1152};
  constexpr int NA = 2 * LAM + 1;
  constexpr int NB = 2 * EL + 1;
  int inu = pr & 0xffff;
  int i1 = pr >> 16;
  const float* ap = ldsA + AOFF[LAM] + inu * NA;
  const float* bp = ldsB + BOFF[EL] + i1 * NB;
  float a[NA];
  float b[NB];
#pragma unroll
  for (int mu = 0; mu < NA; mu++) a[mu] = ap[mu];
#pragma unroll
  for (int m = 0; m < NB; m++) b[m] = bp[m];
  float acc[2 * LV + 1];
#pragma unroll
  for (int M = 0; M <= 2 * LV; M++) acc[M] = 0.0f;
  int p = 0;
#pragma unroll
  for (int mu = 0; mu < NA; mu++) {
#pragma unroll
    for (int m = 0; m < NB; m++) {
      const int Mv = (mu - LAM) + (m - EL);
      if (Mv >= -LV && Mv <= LV) {
        acc[Mv + LV] += cgp[p] * a[mu] * b[m];
        p++;
      }
    }
  }
#pragma unroll
  for (int M = 0; M <= 2 * LV; M++)
    __builtin_nontemporal_store(acc[M], &orow[(size_t)M * SM]);
}

__global__ __launch_bounds__(256) void le_compute_kernel(
    const float* __restrict__ A0, const float* __restrict__ A1,
    const float* __restrict__ A2, const float* __restrict__ A3,
    const float* __restrict__ B0, const float* __restrict__ B1,
    const float* __restrict__ B2, const float* __restrict__ B3,
    const int* __restrict__ pairs, const float* __restrict__ cg,
    Meta meta, float* __restrict__ out) {
  __shared__ float ldsA[4096];
  __shared__ float ldsB[2048];
  int bid = blockIdx.x;
  int s = bid & 1023;   // halves of one sample land on the same XCD (1024%8==0)
  int half = bid >> 10;
  int k = threadIdx.x;

  // stage transposed: lane = feature j -> coalesced global reads,
  // odd-stride LDS writes are bank-conflict-free.
  {
    ldsA[k] = A0[(size_t)s * 256 + k];
#pragma unroll
    for (int mu = 0; mu < 3; mu++)
      ldsA[256 + k * 3 + mu] = A1[(size_t)s * 768 + mu * 256 + k];
#pragma unroll
    for (int mu = 0; mu < 5; mu++)
      ldsA[1024 + k * 5 + mu] = A2[(size_t)s * 1280 + mu * 256 + k];
#pragma unroll
    for (int mu = 0; mu < 7; mu++)
      ldsA[2304 + k * 7 + mu] = A3[(size_t)s * 1792 + mu * 256 + k];
    if (k < 128) {
      ldsB[k] = B0[(size_t)s * 128 + k];
#pragma unroll
      for (int m = 0; m < 3; m++)
        ldsB[128 + k * 3 + m] = B1[(size_t)s * 384 + m * 128 + k];
#pragma unroll
      for (int m = 0; m < 5; m++)
        ldsB[512 + k * 5 + m] = B2[(size_t)s * 640 + m * 128 + k];
#pragma unroll
      for (int m = 0; m < 7; m++)
        ldsB[1152 + k * 7 + m] = B3[(size_t)s * 896 + m * 128 + k];
    }
  }
  __syncthreads();

  float* outs = out + (size_t)s * 65536 + k;
#define RUN(TT, LM, ELV, LV)                                      \
  le_body3<LM, ELV, LV>(ldsA, ldsB, pairs[(TT << 8) + k],         \
                        cg + meta.cumP[TT], outs + meta.outbase[TT]);
  // bodies in outbase-sorted order, interleaved into two balanced halves;
  // each block's stores sweep its 256KB output row near-sequentially.
  if (half == 0) {
    RUN(0, 0, 0, 0)   RUN(18, 2, 2, 0)  RUN(1, 0, 1, 1)   RUN(6, 1, 1, 1)
    RUN(15, 2, 1, 1)  RUN(23, 2, 3, 1)  RUN(38, 3, 3, 1)  RUN(7, 1, 1, 2)
    RUN(11, 1, 3, 2)  RUN(16, 2, 1, 2)  RUN(24, 2, 3, 2)  RUN(33, 3, 2, 2)
    RUN(3, 0, 3, 3)   RUN(12, 1, 3, 3)  RUN(21, 2, 2, 3)  RUN(28, 3, 0, 3)
    RUN(34, 3, 2, 3)  RUN(13, 1, 3, 4)  RUN(26, 2, 3, 4)  RUN(35, 3, 2, 4)
    RUN(27, 2, 3, 5)  RUN(42, 3, 3, 5)
  } else {
    RUN(5, 1, 1, 0)   RUN(37, 3, 3, 0)  RUN(4, 1, 0, 1)   RUN(8, 1, 2, 1)
    RUN(19, 2, 2, 1)  RUN(32, 3, 2, 1)  RUN(2, 0, 2, 2)   RUN(9, 1, 2, 2)
    RUN(14, 2, 0, 2)  RUN(20, 2, 2, 2)  RUN(29, 3, 1, 2)  RUN(39, 3, 3, 2)
    RUN(10, 1, 2, 3)  RUN(17, 2, 1, 3)  RUN(25, 2, 3, 3)  RUN(30, 3, 1, 3)
    RUN(40, 3, 3, 3)  RUN(22, 2, 2, 4)  RUN(31, 3, 1, 4)  RUN(41, 3, 3, 4)
    RUN(36, 3, 2, 5)  RUN(43, 3, 3, 6)
  }
#undef RUN
}

extern "C" void kernel_launch(void* const* d_in, const int* in_sizes, int n_in,
                              void* d_out, int out_size, void* d_ws, size_t ws_size,
                              hipStream_t stream) {
  const float* A0 = (const float*)d_in[0];
  const float* A1 = (const float*)d_in[1];
  const float* A2 = (const float*)d_in[2];
  const float* A3 = (const float*)d_in[3];
  const float* B0 = (const float*)d_in[4];
  const float* B1 = (const float*)d_in[5];
  const float* B2 = (const float*)d_in[6];
  const float* B3 = (const float*)d_in[7];
  float* out = (float*)d_out;

  // workspace carve (4-byte units)
  unsigned* rnd = (unsigned*)d_ws;            // STREAMN u32
  int* pairs = (int*)d_ws + STREAMN;          // 44*256 packed (idx_nu | idx_1<<16)
  float* cg = (float*)(pairs + NTRIP * 256);  // ~820 floats

  // deterministic static metadata (mirrors reference build_structure loops)
  Meta meta;
  int nL[7] = {0, 0, 0, 0, 0, 0, 0};
  for (int lam = 0; lam <= 3; lam++)
    for (int l = 0; l <= 3; l++)
      for (int L = (lam > l ? lam - l : l - lam); L <= lam + l; L++) nL[L]++;
  int Lbase[8];
  Lbase[0] = 0;
  for (int L = 0; L < 7; L++) Lbase[L + 1] = Lbase[L] + (2 * L + 1) * nL[L] * 256;
  int bcnt[7] = {0, 0, 0, 0, 0, 0, 0};
  int t = 0, cum = 0;
  for (int lam = 0; lam <= 3; lam++)
    for (int l = 0; l <= 3; l++)
      for (int L = (lam > l ? lam - l : l - lam); L <= lam + l; L++) {
        meta.lam[t] = lam;
        meta.ell[t] = l;
        meta.LL[t] = L;
        meta.outbase[t] = Lbase[L] + bcnt[L] * 256;
        bcnt[L]++;
        int P = 0;
        for (int mu = 0; mu <= 2 * lam; mu++)
          for (int m = 0; m <= 2 * l; m++) {
            int Mv = (mu - lam) + (m - l);
            if (Mv >= -L && Mv <= L) P++;
          }
        meta.P[t] = P;
        meta.cumP[t] = cum;
        cum += P;
        t++;
      }

  gen_kernel<<<1, 256, 0, stream>>>(rnd, pairs, cg, meta);
  le_compute_kernel<<<2048, 256, 0, stream>>>(
      A0, A1, A2, A3, B0, B1, B2, B3, pairs, cg, meta, out);
}